// Round 4
// baseline (25.721 us; speedup 1.0000x reference)
//
#include <hip/hip_runtime.h>

// PyBlaz 8x8 block DCT + int8 quantization, one thread per 8x8 block.
// R3: single-wave workgroups (64 threads). The LDS output-staging exchange
// is intra-wave, so the __syncthreads compiles to just an lgkmcnt wait (no
// s_barrier) -> no inter-wave phase coupling; 16 independent waves/CU
// stagger their load/store bursts into a smooth mixed HBM stream.
//
// Input: x (4096 x 4096 fp32). Outputs (concatenated in d_out as float32):
//   [0, 262144)               biggest (512 x 512)
//   [262144, 262144+16777216)  indices as float (512 x 512 x 64)

#define IMG_W 4096
#define NB    512          // blocks per dim
#define NBLK  (NB * NB)    // 262144 total 8x8 blocks
#define WG    64

__global__ __launch_bounds__(WG) void dct_quant_kernel(
    const float* __restrict__ x,
    float* __restrict__ out_big,
    float* __restrict__ out_idx)
{
    // 64 threads x 16 packed u32 (64 int8) each; stride 17 (odd) makes the
    // per-thread column scatter a perfect bank permutation.
    __shared__ unsigned int lds[WG * 17];

    const int t   = threadIdx.x;
    const int bid = blockIdx.x * WG + t;    // 0..NBLK-1
    const int bi  = bid >> 9;               // block row
    const int bj  = bid & (NB - 1);         // block col

    // Orthonormal DCT-II matrix D[e][f] = scale(f) * cos(pi*(2e+1)*f/16),
    // baked as literals so the fully-unrolled loops constant-fold.
    const float s0 = 0.35355339059327373f;   // sqrt(1/8)
    const float d1 = 0.49039264020161522f;
    const float d2 = 0.46193976625564337f;
    const float d3 = 0.41573480615127262f;
    const float d4 = 0.35355339059327379f;
    const float d5 = 0.27778511650980114f;
    const float d6 = 0.19134171618254492f;
    const float d7 = 0.09754516100806413f;

    const float D[8][8] = {
        { s0,  d1,  d2,  d3,  d4,  d5,  d6,  d7},
        { s0,  d3,  d6, -d7, -d4, -d1, -d2, -d5},
        { s0,  d5, -d6, -d1, -d4,  d7,  d2,  d3},
        { s0,  d7, -d2, -d5,  d4,  d3, -d6, -d1},
        { s0, -d7, -d2,  d5,  d4, -d3, -d6,  d1},
        { s0, -d5, -d6,  d1, -d4, -d7,  d2, -d3},
        { s0, -d3,  d6,  d7, -d4,  d1, -d2,  d5},
        { s0, -d1,  d2, -d3,  d4, -d5,  d6, -d7},
    };

    const float* p = x + (size_t)(bi * 8) * IMG_W + (size_t)bj * 8;

    float C[8][8];
#pragma unroll
    for (int g = 0; g < 8; ++g)
#pragma unroll
        for (int h = 0; h < 8; ++h) C[g][h] = 0.0f;

    // C = D^T * X * D, accumulated row-by-row:
    //   tmp[h] = sum_f X[e][f] * D[f][h]   (row transform)
    //   C[g][h] += D[e][g] * tmp[h]        (column transform)
#pragma unroll
    for (int e = 0; e < 8; ++e) {
        const float4 r0 = *reinterpret_cast<const float4*>(p + (size_t)e * IMG_W);
        const float4 r1 = *reinterpret_cast<const float4*>(p + (size_t)e * IMG_W + 4);
        const float row[8] = {r0.x, r0.y, r0.z, r0.w, r1.x, r1.y, r1.z, r1.w};

        float tmp[8];
#pragma unroll
        for (int h = 0; h < 8; ++h) {
            float acc = row[0] * D[0][h];
#pragma unroll
            for (int f = 1; f < 8; ++f) acc = fmaf(row[f], D[f][h], acc);
            tmp[h] = acc;
        }
#pragma unroll
        for (int g = 0; g < 8; ++g) {
#pragma unroll
            for (int h = 0; h < 8; ++h) C[g][h] = fmaf(D[e][g], tmp[h], C[g][h]);
        }
    }

    // Per-block abs-max
    float big = 0.0f;
#pragma unroll
    for (int g = 0; g < 8; ++g)
#pragma unroll
        for (int h = 0; h < 8; ++h) big = fmaxf(big, fabsf(C[g][h]));

    out_big[bid] = big;   // 64 consecutive dwords -> coalesced

    const float safe = (big == 0.0f) ? 1.0f : big;
    const float inv  = 127.0f / safe;

    // Quantize to int8, pack 4 per u32, stage in LDS.
#pragma unroll
    for (int g = 0; g < 8; ++g) {
        int q[8];
#pragma unroll
        for (int h = 0; h < 8; ++h) q[h] = (int)rintf(C[g][h] * inv);  // [-127,127]
        const unsigned int w0 = (q[0] & 0xff) | ((q[1] & 0xff) << 8) |
                                ((q[2] & 0xff) << 16) | ((unsigned)(q[3] & 0xff) << 24);
        const unsigned int w1 = (q[4] & 0xff) | ((q[5] & 0xff) << 8) |
                                ((q[6] & 0xff) << 16) | ((unsigned)(q[7] & 0xff) << 24);
        lds[t * 17 + 2 * g]     = w0;
        lds[t * 17 + 2 * g + 1] = w1;
    }

    __syncthreads();   // single-wave WG: compiles to lgkmcnt wait, no s_barrier

    // Coalesced copy-out: 1024 float4s per WG; each float4 unpacks one u32.
    float4* og = reinterpret_cast<float4*>(out_idx) + (size_t)blockIdx.x * 1024;
#pragma unroll
    for (int k = 0; k < 16; ++k) {
        const int F = k * WG + t;           // flat u32 index in this WG's region
        const unsigned int w = lds[(F >> 4) * 17 + (F & 15)];
        float4 q;
        q.x = (float)(int)(signed char)(w       & 0xff);
        q.y = (float)(int)(signed char)((w >> 8)  & 0xff);
        q.z = (float)(int)(signed char)((w >> 16) & 0xff);
        q.w = (float)(int)(signed char)(w >> 24);
        og[F] = q;
    }
}

extern "C" void kernel_launch(void* const* d_in, const int* in_sizes, int n_in,
                              void* d_out, int out_size, void* d_ws, size_t ws_size,
                              hipStream_t stream) {
    const float* x = (const float*)d_in[0];
    float* out = (float*)d_out;
    float* out_big = out;          // 262144 floats
    float* out_idx = out + NBLK;   // 16777216 floats

    dct_quant_kernel<<<NBLK / WG, WG, 0, stream>>>(x, out_big, out_idx);
}